// Round 2
// baseline (246.812 us; speedup 1.0000x reference)
//
#include <hip/hip_runtime.h>
#include <hip/hip_bf16.h>

// Problem constants: N tokens, D d_model, E experts, H hidden, K top-k
#define NTOK 4096
#define DM   512
#define NE   32
#define HD   128
#define TK   4
#define NBLK 512   // fused kernel grid: 2 blocks/CU, guaranteed co-resident

typedef unsigned short u16;
typedef unsigned int   u32;
typedef u16   u16x4 __attribute__((ext_vector_type(4)));
typedef u16   u16x8 __attribute__((ext_vector_type(8)));
typedef short short8 __attribute__((ext_vector_type(8)));
typedef float f32x4 __attribute__((ext_vector_type(4)));

__device__ __forceinline__ u16 f2bf(float f) {
    union { float f; u32 u; } v; v.f = f;
    return (u16)((v.u + 0x7FFFu + ((v.u >> 16) & 1u)) >> 16);   // RNE
}
__device__ __forceinline__ float bf2f(u16 h) {
    union { u32 u; float f; } v; v.u = ((u32)h) << 16; return v.f;
}

// Device-scope grid barrier: all NBLK blocks are co-resident by construction
// (LDS 59.7KB*2 <= 160KB/CU, VGPR capped at 256 via __launch_bounds__(256,2)).
// Release on arrive makes this block's global writes device-visible (L2 wb);
// acquire on the spin load invalidates stale lines before post-barrier reads.
__device__ __forceinline__ void grid_sync(u32* bar, u32 target) {
    __syncthreads();                 // drains each wave's vmcnt before arrive
    if (threadIdx.x == 0) {
        __hip_atomic_fetch_add(bar, 1u, __ATOMIC_ACQ_REL, __HIP_MEMORY_SCOPE_AGENT);
        while (__hip_atomic_load(bar, __ATOMIC_ACQUIRE, __HIP_MEMORY_SCOPE_AGENT) < target)
            __builtin_amdgcn_s_sleep(2);
    }
    __syncthreads();
}

// =====================================================================
// Fused: prep (swizzle + router) -> barrier -> expert MLP -> barrier -> combine
// =====================================================================
__global__ __launch_bounds__(256, 2) void fused_moe(
        const float* __restrict__ x, const float* __restrict__ sel,
        const float* __restrict__ w1, const float* __restrict__ w2,
        int* __restrict__ counts_pad, u32* __restrict__ bar,
        int* __restrict__ tok_list, float* __restrict__ gate_list,
        u16* __restrict__ xbf, u16* __restrict__ wf1, u16* __restrict__ wf2,
        u16* __restrict__ part, float* __restrict__ out) {
    __shared__ __align__(16) float  xs[8][520];
    __shared__ double sc[8][33];
    __shared__ int    s_cnt[NE];
    __shared__ int    s_ent[32];
    __shared__ float  s_gate[32];
    __shared__ __align__(16) u16 Hm[32][136];       // 272B stride
    __shared__ __align__(16) u16 Ct[32][520];       // 1040B stride

    int tid = threadIdx.x;
    int wv = tid >> 6, lane = tid & 63;
    int b = blockIdx.x;

    // ---------- phase 1a: weight swizzle fp32 -> bf16 fragment-major (2 units) ----------
    {
        int m = lane & 15, q = lane >> 4;
#pragma unroll
        for (int un = 0; un < 2; ++un) {
            int bs = b + un * NBLK;                 // 0..1023
            int f0 = (bs * 4 + wv) * 2;
            const float* in[2]; u16* outp[2]; int Nd[2];
#pragma unroll
            for (int u = 0; u < 2; ++u) {
                int w = f0 + u;
                if (w < 4096) {
                    int e = w >> 7, rem = w & 127, ks = rem >> 3, nt = rem & 7;
                    in[u] = w1 + (size_t)e * DM * HD + (size_t)(32 * ks + q * 8) * HD + 16 * nt + m;
                    Nd[u] = HD;
                    outp[u] = wf1 + (size_t)w * 512 + lane * 8;
                } else {
                    int wl = w - 4096, e = wl >> 7, rem = wl & 127, ks = rem >> 5, nt = rem & 31;
                    in[u] = w2 + (size_t)e * HD * DM + (size_t)(32 * ks + q * 8) * DM + 16 * nt + m;
                    Nd[u] = DM;
                    outp[u] = wf2 + (size_t)wl * 512 + lane * 8;
                }
            }
            float v[2][8];
#pragma unroll
            for (int u = 0; u < 2; ++u)
#pragma unroll
                for (int j = 0; j < 8; ++j) v[u][j] = in[u][(size_t)j * Nd[u]];
#pragma unroll
            for (int u = 0; u < 2; ++u) {
                u16x8 h;
#pragma unroll
                for (int j = 0; j < 8; ++j) h[j] = f2bf(v[u][j]);
                *(u16x8*)outp[u] = h;
            }
        }
    }

    // ---------- phase 1b: router, 8 tokens/block (fp64 dots, exact ordering) ----------
    {
        int tb = b * 8;
#pragma unroll
        for (int rep = 0; rep < 4; ++rep) {
            int idx = (rep * 256 + tid) * 4;        // element in 8x512 tile
            int row = idx >> 9, col = idx & 511;
            f32x4 v = *(const f32x4*)(x + (size_t)(tb + row) * DM + col);
            *(f32x4*)&xs[row][col] = v;
            u16x4 h;
#pragma unroll
            for (int j = 0; j < 4; ++j) h[j] = f2bf(v[j]);
            *(u16x4*)(xbf + (size_t)(tb + row) * DM + col) = h;
        }
        __syncthreads();

        // thread: tok = tid&7, e = tid>>3; full 512-long fp64 dot, 4 chains
        int tok = tid & 7, e = tid >> 3;
        const float* sp = sel + (size_t)e * DM;
        const float* xp = xs[tok];
        double pa = 0.0, pb = 0.0, pc = 0.0, pd = 0.0;
#pragma unroll 4
        for (int j = 0; j < 512; j += 16) {
            f32x4 x0 = *(const f32x4*)(xp + j);
            f32x4 x1 = *(const f32x4*)(xp + j + 4);
            f32x4 x2 = *(const f32x4*)(xp + j + 8);
            f32x4 x3 = *(const f32x4*)(xp + j + 12);
            f32x4 s0 = *(const f32x4*)(sp + j);
            f32x4 s1 = *(const f32x4*)(sp + j + 4);
            f32x4 s2 = *(const f32x4*)(sp + j + 8);
            f32x4 s3 = *(const f32x4*)(sp + j + 12);
#pragma unroll
            for (int k = 0; k < 4; ++k) {
                pa = fma((double)x0[k], (double)s0[k], pa);
                pb = fma((double)x1[k], (double)s1[k], pb);
                pc = fma((double)x2[k], (double)s2[k], pc);
                pd = fma((double)x3[k], (double)s3[k], pd);
            }
        }
        sc[tok][e] = (pa + pb) + (pc + pd);
        __syncthreads();

        if (tid < 8) {
            int t = tb + tid;
            unsigned mask = 0;
            for (int k = 0; k < TK; ++k) {
                double best = -1e300; int be = 0;
                for (int ee = 0; ee < NE; ++ee) {
                    double v = sc[tid][ee];
                    if (!((mask >> ee) & 1u) && v > best) { best = v; be = ee; }
                }
                mask |= 1u << be;
                float gate = 1.0f / (1.0f + __expf(-(float)best));
                int pos = atomicAdd(&counts_pad[32 * be], 1);    // own 128-B line/expert
                tok_list[be * NTOK + pos]  = (k << 16) | t;
                gate_list[be * NTOK + pos] = gate;
            }
        }
    }

    grid_sync(bar, NBLK);                           // prep complete, device-visible

    // ---------- phase 2: expert MLP, per-XCD tile loop (32-row tiles) ----------
    {
        if (tid < NE)
            s_cnt[tid] = __hip_atomic_load(counts_pad + 32 * tid,
                                           __ATOMIC_RELAXED, __HIP_MEMORY_SCOPE_AGENT);
        __syncthreads();

        int xcd = b & 7, idx0 = b >> 3;             // 64 blocks per group
        int c0 = s_cnt[xcd], c1 = s_cnt[xcd + 8], c2 = s_cnt[xcd + 16], c3 = s_cnt[xcd + 24];
        int n0 = (c0 + 31) >> 5, n1 = (c1 + 31) >> 5, n2 = (c2 + 31) >> 5, n3 = (c3 + 31) >> 5;
        int tot = n0 + n1 + n2 + n3;

        int m = lane & 15, q = lane >> 4;
        int r = wv >> 1, c = wv & 1;                // GEMM1: rows 16r..+16, cols 64c..+64

        for (int idx = idx0; idx < tot; idx += 64) {
            int e2, t2;
            if (idx < n0)                { e2 = xcd;      t2 = idx; }
            else if (idx < n0 + n1)      { e2 = xcd + 8;  t2 = idx - n0; }
            else if (idx < n0 + n1 + n2) { e2 = xcd + 16; t2 = idx - n0 - n1; }
            else                         { e2 = xcd + 24; t2 = idx - n0 - n1 - n2; }
            int cc = s_cnt[e2];
            int rows = cc - t2 * 32; if (rows > 32) rows = 32;

            __syncthreads();                        // prev iter's Ct/s_ent readers done
            if (tid < 32) {
                int base = e2 * NTOK + t2 * 32;
                bool val = tid < rows;
                s_ent[tid]  = tok_list[base + (val ? tid : 0)];
                s_gate[tid] = val ? gate_list[base + tid] : 0.0f;
            }
            __syncthreads();

            const u16* w1f = wf1 + (size_t)e2 * (128 * 512);
            const u16* w2f = wf2 + (size_t)e2 * (128 * 512);
            const u16* a0 = xbf + (size_t)(s_ent[16 * r + m] & 0xFFFF) * DM + q * 8;

            // GEMM1: k-steps in pairs, double-buffered
            short8 ab[2][2];
            short8 bb[2][2][4];
#pragma unroll
            for (int kk = 0; kk < 2; ++kk) {
                ab[0][kk] = *(const short8*)(a0 + 32 * kk);
                const u16* bp = w1f + (size_t)kk * 4096 + (size_t)(4 * c) * 512 + lane * 8;
#pragma unroll
                for (int n = 0; n < 4; ++n) bb[0][kk][n] = *(const short8*)(bp + n * 512);
            }
            f32x4 acc[4];
#pragma unroll
            for (int n = 0; n < 4; ++n) acc[n] = (f32x4){0.f, 0.f, 0.f, 0.f};

#pragma unroll
            for (int kp = 0; kp < 8; ++kp) {
                int cur = kp & 1, nxt = cur ^ 1;
                if (kp < 7) {
                    int ks0 = 2 * (kp + 1);
#pragma unroll
                    for (int kk = 0; kk < 2; ++kk) {
                        ab[nxt][kk] = *(const short8*)(a0 + 32 * (ks0 + kk));
                        const u16* bp = w1f + (size_t)(ks0 + kk) * 4096 + (size_t)(4 * c) * 512 + lane * 8;
#pragma unroll
                        for (int n = 0; n < 4; ++n) bb[nxt][kk][n] = *(const short8*)(bp + n * 512);
                    }
                }
#pragma unroll
                for (int kk = 0; kk < 2; ++kk)
#pragma unroll
                    for (int n = 0; n < 4; ++n)
                        acc[n] = __builtin_amdgcn_mfma_f32_16x16x32_bf16(ab[cur][kk],
                                                                         bb[cur][kk][n],
                                                                         acc[n], 0, 0, 0);
            }

            // relu * gate -> Hm
            {
                int rb = 16 * r + q * 4;
#pragma unroll
                for (int n = 0; n < 4; ++n)
#pragma unroll
                    for (int rr = 0; rr < 4; ++rr)
                        Hm[rb + rr][64 * c + 16 * n + m] =
                            f2bf(fmaxf(acc[n][rr], 0.f) * s_gate[rb + rr]);
            }

            // GEMM2: wave owns cols [128*wv, +128); w2 frags double-buffered per k-slice
            short8 cb[2][8];
            {
                const u16* bp = w2f + (size_t)(wv * 8) * 512 + lane * 8;
#pragma unroll
                for (int n = 0; n < 8; ++n) cb[0][n] = *(const short8*)(bp + n * 512);
            }
            __syncthreads();                        // Hm ready

            f32x4 acc2[2][8];
#pragma unroll
            for (int i = 0; i < 2; ++i)
#pragma unroll
                for (int n = 0; n < 8; ++n) acc2[i][n] = (f32x4){0.f, 0.f, 0.f, 0.f};
#pragma unroll
            for (int ks = 0; ks < 4; ++ks) {
                int cur = ks & 1, nxt = cur ^ 1;
                if (ks < 3) {
                    const u16* bp = w2f + (size_t)((ks + 1) * 32 + wv * 8) * 512 + lane * 8;
#pragma unroll
                    for (int n = 0; n < 8; ++n) cb[nxt][n] = *(const short8*)(bp + n * 512);
                }
                short8 h0 = *(const short8*)&Hm[m][32 * ks + q * 8];
                short8 h1 = *(const short8*)&Hm[16 + m][32 * ks + q * 8];
#pragma unroll
                for (int n = 0; n < 8; ++n) {
                    acc2[0][n] = __builtin_amdgcn_mfma_f32_16x16x32_bf16(h0, cb[cur][n], acc2[0][n], 0, 0, 0);
                    acc2[1][n] = __builtin_amdgcn_mfma_f32_16x16x32_bf16(h1, cb[cur][n], acc2[1][n], 0, 0, 0);
                }
            }

            // C-layout -> LDS transpose (each wave writes its 128-col stripe)
#pragma unroll
            for (int i = 0; i < 2; ++i) {
                int rb = 16 * i + q * 4;
#pragma unroll
                for (int n = 0; n < 8; ++n)
#pragma unroll
                    for (int rr = 0; rr < 4; ++rr)
                        Ct[rb + rr][128 * wv + 16 * n + m] = f2bf(acc2[i][n][rr]);
            }
            __syncthreads();                        // Ct complete
            // contiguous row stores into part slots
#pragma unroll
            for (int rep = 0; rep < 8; ++rep) {
                int rl = rep * 4 + wv;              // 0..31
                u16x8 v = *(const u16x8*)&Ct[rl][lane * 8];
                if (rl < rows) {
                    int en = s_ent[rl];
                    int tk = en & 0xFFFF, sl2 = en >> 16;
                    *(u16x8*)(part + ((size_t)sl2 * NTOK + tk) * DM + lane * 8) = v;
                }
            }
        }
    }

    grid_sync(bar, 2u * NBLK);                      // all part slots written

    // ---------- phase 3: combine out[t][c] = sum_k part[k][t][c] (2 units) ----------
#pragma unroll
    for (int rep = 0; rep < 2; ++rep) {
        size_t off = (((size_t)b + (size_t)rep * NBLK) * 256 + tid) * 8;
        float s[8] = {0, 0, 0, 0, 0, 0, 0, 0};
#pragma unroll
        for (int k = 0; k < TK; ++k) {
            u16x8 p = *(const u16x8*)(part + (size_t)k * NTOK * DM + off);
#pragma unroll
            for (int j = 0; j < 8; ++j) s[j] += bf2f(p[j]);
        }
        *(f32x4*)(out + off)     = (f32x4){s[0], s[1], s[2], s[3]};
        *(f32x4*)(out + off + 4) = (f32x4){s[4], s[5], s[6], s[7]};
    }
}

// =====================================================================
// Fallback path (only if workspace too small for `part`): round-1 kernels
// =====================================================================
__global__ __launch_bounds__(256) void prep_kernel(const float* __restrict__ x,
                                                   const float* __restrict__ sel,
                                                   const float* __restrict__ w1,
                                                   const float* __restrict__ w2,
                                                   int* __restrict__ counts_pad,
                                                   int* __restrict__ tok_list,
                                                   float* __restrict__ gate_list,
                                                   u16* __restrict__ xbf,
                                                   u16* __restrict__ wf1,
                                                   u16* __restrict__ wf2) {
    __shared__ float  xs[4][520];
    __shared__ double sc[4][33];
    int tid = threadIdx.x;
    int wv = tid >> 6, lane = tid & 63;

    if (blockIdx.x >= 1024) {
        int m = lane & 15, q = lane >> 4;
        int f0 = ((blockIdx.x - 1024) * 4 + wv) * 2;
        const float* in[2]; u16* outp[2]; int Nd[2];
#pragma unroll
        for (int u = 0; u < 2; ++u) {
            int w = f0 + u;
            if (w < 4096) {
                int e = w >> 7, rem = w & 127, ks = rem >> 3, nt = rem & 7;
                in[u] = w1 + (size_t)e * DM * HD + (size_t)(32 * ks + q * 8) * HD + 16 * nt + m;
                Nd[u] = HD;
                outp[u] = wf1 + (size_t)w * 512 + lane * 8;
            } else {
                int wl = w - 4096, e = wl >> 7, rem = wl & 127, ks = rem >> 5, nt = rem & 31;
                in[u] = w2 + (size_t)e * HD * DM + (size_t)(32 * ks + q * 8) * DM + 16 * nt + m;
                Nd[u] = DM;
                outp[u] = wf2 + (size_t)wl * 512 + lane * 8;
            }
        }
        float v[2][8];
#pragma unroll
        for (int u = 0; u < 2; ++u)
#pragma unroll
            for (int j = 0; j < 8; ++j) v[u][j] = in[u][(size_t)j * Nd[u]];
#pragma unroll
        for (int u = 0; u < 2; ++u) {
            u16x8 h;
#pragma unroll
            for (int j = 0; j < 8; ++j) h[j] = f2bf(v[u][j]);
            *(u16x8*)outp[u] = h;
        }
        return;
    }

    int tb = blockIdx.x * 4;
#pragma unroll
    for (int rep = 0; rep < 2; ++rep) {
        int idx = (rep * 256 + tid) * 4;
        int row = idx >> 9, col = idx & 511;
        f32x4 v = *(const f32x4*)(x + (size_t)(tb + row) * DM + col);
        *(f32x4*)&xs[row][col] = v;
        u16x4 h;
#pragma unroll
        for (int j = 0; j < 4; ++j) h[j] = f2bf(v[j]);
        *(u16x4*)(xbf + (size_t)(tb + row) * DM + col) = h;
    }
    __syncthreads();

    int tok = tid & 3, seg = (tid >> 2) & 1, e = tid >> 3;
    const float* sp = sel + (size_t)e * DM + seg * 256;
    const float* xp = &xs[tok][seg * 256];
    double pa = 0.0, pb = 0.0, pc = 0.0, pd = 0.0;
#pragma unroll 4
    for (int j = 0; j < 256; j += 16) {
        f32x4 x0 = *(const f32x4*)(xp + j);
        f32x4 x1 = *(const f32x4*)(xp + j + 4);
        f32x4 x2 = *(const f32x4*)(xp + j + 8);
        f32x4 x3 = *(const f32x4*)(xp + j + 12);
        f32x4 s0 = *(const f32x4*)(sp + j);
        f32x4 s1 = *(const f32x4*)(sp + j + 4);
        f32x4 s2 = *(const f32x4*)(sp + j + 8);
        f32x4 s3 = *(const f32x4*)(sp + j + 12);
#pragma unroll
        for (int k = 0; k < 4; ++k) {
            pa = fma((double)x0[k], (double)s0[k], pa);
            pb = fma((double)x1[k], (double)s1[k], pb);
            pc = fma((double)x2[k], (double)s2[k], pc);
            pd = fma((double)x3[k], (double)s3[k], pd);
        }
    }
    double p = (pa + pb) + (pc + pd);
    p += __shfl_xor(p, 4);
    if (seg == 0) sc[tok][e] = p;
    __syncthreads();

    if (tid < 4) {
        int t = tb + tid;
        unsigned mask = 0;
        for (int k = 0; k < TK; ++k) {
            double best = -1e300; int be = 0;
            for (int ee = 0; ee < NE; ++ee) {
                double v = sc[tid][ee];
                if (!((mask >> ee) & 1u) && v > best) { best = v; be = ee; }
            }
            mask |= 1u << be;
            float gate = 1.0f / (1.0f + __expf(-(float)best));
            int pos = atomicAdd(&counts_pad[32 * be], 1);
            tok_list[be * NTOK + pos]  = (k << 16) | t;
            gate_list[be * NTOK + pos] = gate;
        }
    }
}

__global__ __launch_bounds__(256, 2) void moe_mlp_kernel(const u16* __restrict__ xbf,
                                                         const u16* __restrict__ wf1,
                                                         const u16* __restrict__ wf2,
                                                         const int* __restrict__ counts_pad,
                                                         const int* __restrict__ tok_list,
                                                         const float* __restrict__ gate_list,
                                                         float* __restrict__ out) {
    __shared__ int   s_cnt[NE];
    __shared__ int   s_ent[32];
    __shared__ float s_gate[32];
    __shared__ __align__(16) u16 Hm[32][136];
    __shared__ __align__(16) u16 Ct[32][520];

    int tid = threadIdx.x;
    if (tid < NE) s_cnt[tid] = counts_pad[32 * tid];
    __syncthreads();

    int b = blockIdx.x;
    int xcd = b & 7, idx = b >> 3;
    int e = -1, t = 0, rows = 0, pre = 0;
#pragma unroll
    for (int j = 0; j < 4; ++j) {
        int ee = xcd + 8 * j;
        int cc = s_cnt[ee];
        int nt = (cc + 31) >> 5;
        if (e < 0 && idx < pre + nt) { e = ee; t = idx - pre; rows = cc - t * 32; if (rows > 32) rows = 32; }
        pre += nt;
    }
    if (e < 0) return;

    if (tid < 32) {
        int base = e * NTOK + t * 32;
        bool val = tid < rows;
        s_ent[tid]  = tok_list[base + (val ? tid : 0)];
        s_gate[tid] = val ? gate_list[base + tid] : 0.0f;
    }
    __syncthreads();

    int wv = tid >> 6, lane = tid & 63, m = lane & 15, q = lane >> 4;
    int r = wv >> 1, c = wv & 1;
    const u16* w1f = wf1 + (size_t)e * (128 * 512);
    const u16* w2f = wf2 + (size_t)e * (128 * 512);
    const u16* a0 = xbf + (size_t)(s_ent[16 * r + m] & 0xFFFF) * DM + q * 8;

    short8 ab[2][2];
    short8 bb[2][2][4];
#pragma unroll
    for (int kk = 0; kk < 2; ++kk) {
        ab[0][kk] = *(const short8*)(a0 + 32 * kk);
        const u16* bp = w1f + (size_t)kk * 4096 + (size_t)(4 * c) * 512 + lane * 8;
#pragma unroll
        for (int n = 0; n < 4; ++n) bb[0][kk][n] = *(const short8*)(bp + n * 512);
    }
    f32x4 acc[4];
#pragma unroll
    for (int n = 0; n < 4; ++n) acc[n] = (f32x4){0.f, 0.f, 0.f, 0.f};

#pragma unroll
    for (int kp = 0; kp < 8; ++kp) {
        int cur = kp & 1, nxt = cur ^ 1;
        if (kp < 7) {
            int ks0 = 2 * (kp + 1);
#pragma unroll
            for (int kk = 0; kk < 2; ++kk) {
                ab[nxt][kk] = *(const short8*)(a0 + 32 * (ks0 + kk));
                const u16* bp = w1f + (size_t)(ks0 + kk) * 4096 + (size_t)(4 * c) * 512 + lane * 8;
#pragma unroll
                for (int n = 0; n < 4; ++n) bb[nxt][kk][n] = *(const short8*)(bp + n * 512);
            }
        }
#pragma unroll
        for (int kk = 0; kk < 2; ++kk)
#pragma unroll
            for (int n = 0; n < 4; ++n)
                acc[n] = __builtin_amdgcn_mfma_f32_16x16x32_bf16(ab[cur][kk], bb[cur][kk][n],
                                                                 acc[n], 0, 0, 0);
    }

    {
        int rb = 16 * r + q * 4;
#pragma unroll
        for (int n = 0; n < 4; ++n)
#pragma unroll
            for (int rr = 0; rr < 4; ++rr)
                Hm[rb + rr][64 * c + 16 * n + m] = f2bf(fmaxf(acc[n][rr], 0.f) * s_gate[rb + rr]);
    }

    short8 cb[2][8];
    {
        const u16* bp = w2f + (size_t)(wv * 8) * 512 + lane * 8;
#pragma unroll
        for (int n = 0; n < 8; ++n) cb[0][n] = *(const short8*)(bp + n * 512);
    }
    __syncthreads();

    f32x4 acc2[2][8];
#pragma unroll
    for (int i = 0; i < 2; ++i)
#pragma unroll
        for (int n = 0; n < 8; ++n) acc2[i][n] = (f32x4){0.f, 0.f, 0.f, 0.f};
#pragma unroll
    for (int ks = 0; ks < 4; ++ks) {
        int cur = ks & 1, nxt = cur ^ 1;
        if (ks < 3) {
            const u16* bp = w2f + (size_t)((ks + 1) * 32 + wv * 8) * 512 + lane * 8;
#pragma unroll
            for (int n = 0; n < 8; ++n) cb[nxt][n] = *(const short8*)(bp + n * 512);
        }
        short8 h0 = *(const short8*)&Hm[m][32 * ks + q * 8];
        short8 h1 = *(const short8*)&Hm[16 + m][32 * ks + q * 8];
#pragma unroll
        for (int n = 0; n < 8; ++n) {
            acc2[0][n] = __builtin_amdgcn_mfma_f32_16x16x32_bf16(h0, cb[cur][n], acc2[0][n], 0, 0, 0);
            acc2[1][n] = __builtin_amdgcn_mfma_f32_16x16x32_bf16(h1, cb[cur][n], acc2[1][n], 0, 0, 0);
        }
    }

#pragma unroll
    for (int i = 0; i < 2; ++i) {
        int rb = 16 * i + q * 4;
#pragma unroll
        for (int n = 0; n < 8; ++n)
#pragma unroll
            for (int rr = 0; rr < 4; ++rr)
                Ct[rb + rr][128 * wv + 16 * n + m] = f2bf(acc2[i][n][rr]);
    }
    __syncthreads();
#pragma unroll
    for (int rep = 0; rep < 8; ++rep) {
        int rl = rep * 4 + wv;
        u16x8 v = *(const u16x8*)&Ct[rl][lane * 8];
        if (rl < rows) {
            int en = s_ent[rl];
            int tk = en & 0xFFFF;
            float* op = out + (size_t)tk * DM + lane * 8;
#pragma unroll
            for (int j = 0; j < 8; ++j) atomicAdd(&op[j], bf2f(v[j]));
        }
    }
}

extern "C" void kernel_launch(void* const* d_in, const int* in_sizes, int n_in,
                              void* d_out, int out_size, void* d_ws, size_t ws_size,
                              hipStream_t stream) {
    (void)in_sizes; (void)n_in; (void)out_size;
    const float* x   = (const float*)d_in[0];   // [N, D]
    const float* sel = (const float*)d_in[1];   // [E, D]
    const float* w1  = (const float*)d_in[2];   // [E, D, H]
    const float* w2  = (const float*)d_in[3];   // [E, H, D]
    float* out = (float*)d_out;                 // [N, D]

    char* ws = (char*)d_ws;
    int*   counts_pad = (int*)(ws);                                  // [0, 4096)
    u32*   bar        = (u32*)(ws + 4096);                           // [4096, 4352) own lines
    int*   tok_list   = (int*)(ws + 4352);                           // 512 KB
    float* gate_list  = (float*)(ws + 4352 + (size_t)NE * NTOK * 4); // 512 KB
    u16*   xbf  = (u16*)(ws + 4352 + (size_t)NE * NTOK * 8);         // 4 MB
    u16*   wf1  = xbf + (size_t)NTOK * DM;                           // 4 MB
    u16*   wf2  = wf1 + (size_t)NE * HD * DM;                        // 4 MB
    u16*   part = wf2 + (size_t)NE * HD * DM;                        // 16.8 MB

    size_t need = 4352 + (size_t)NE * NTOK * 8 + (size_t)NTOK * DM * 2
                + 2 * (size_t)NE * HD * DM * 2 + (size_t)TK * NTOK * DM * 2;

    if (ws_size >= need) {
        // zero counts + barrier counter in one tiny node
        hipMemsetAsync(ws, 0, 4352, stream);
        fused_moe<<<NBLK, 256, 0, stream>>>(x, sel, w1, w2, counts_pad, bar,
                                            tok_list, gate_list, xbf, wf1, wf2,
                                            part, out);
    } else {
        // fallback: 3-launch path with fp32 atomics (no part buffer)
        hipMemsetAsync(counts_pad, 0, 4096, stream);
        hipMemsetAsync(d_out, 0, (size_t)NTOK * DM * sizeof(float), stream);
        prep_kernel<<<2048, 256, 0, stream>>>(x, sel, w1, w2, counts_pad, tok_list,
                                              gate_list, xbf, wf1, wf2);
        moe_mlp_kernel<<<4096, 256, 0, stream>>>(xbf, wf1, wf2, counts_pad, tok_list,
                                                 gate_list, out);
    }
}

// Round 3
// 123.218 us; speedup vs baseline: 2.0030x; 2.0030x over previous
//
#include <hip/hip_runtime.h>
#include <hip/hip_bf16.h>

// Problem constants: N tokens, D d_model, E experts, H hidden, K top-k
#define NTOK 4096
#define DM   512
#define NE   32
#define HD   128
#define TK   4

typedef unsigned short u16;
typedef unsigned int   u32;
typedef u16   u16x4 __attribute__((ext_vector_type(4)));
typedef u16   u16x8 __attribute__((ext_vector_type(8)));
typedef short short8 __attribute__((ext_vector_type(8)));
typedef float f32x4 __attribute__((ext_vector_type(4)));

__device__ __forceinline__ u16 f2bf(float f) {
    union { float f; u32 u; } v; v.f = f;
    return (u16)((v.u + 0x7FFFu + ((v.u >> 16) & 1u)) >> 16);   // RNE
}
__device__ __forceinline__ float bf2f(u16 h) {
    union { u32 u; float f; } v; v.u = ((u32)h) << 16; return v.f;
}

// ---------------- fused prep ----------------
// blocks [0,256):     router, 16 tokens/block (fp64 full-512 dots; LDS-aggregated
//                     per-expert appends: ONE atomicAdd per (block,expert))
// blocks [256,1280):  weight swizzle fp32 -> bf16 fragment-major
//   frag[wl][lane][j] = in[e][32*ks + (lane>>4)*8 + j][16*nt + (lane&15)]
__global__ __launch_bounds__(256) void prep_kernel(const float* __restrict__ x,
                                                   const float* __restrict__ sel,
                                                   const float* __restrict__ w1,
                                                   const float* __restrict__ w2,
                                                   int* __restrict__ counts_pad,
                                                   int* __restrict__ tok_list,
                                                   float* __restrict__ gate_list,
                                                   u16* __restrict__ xbf,
                                                   u16* __restrict__ wf1,
                                                   u16* __restrict__ wf2) {
    // xs row stride 524 floats: 524 % 32 == 12 -> the 8 tok-rows touched by one
    // wave-instr land on banks {0,12,24,4,16,28,8,20} (x4 for b128) = all 32 banks
    // exactly once -> conflict-free ds_read_b128.
    __shared__ __align__(16) float  xs[16][524];    // 33.5 KB
    __shared__ double sc[16][33];                   // 4.2 KB
    __shared__ int    pk_e[64];
    __shared__ float  pk_g[64];
    int tid = threadIdx.x;
    int wv = tid >> 6, lane = tid & 63;

    if (blockIdx.x >= 256) {
        // ---- weight swizzle: 2 fragments per wave (unchanged from round-1) ----
        int m = lane & 15, q = lane >> 4;
        int f0 = ((blockIdx.x - 256) * 4 + wv) * 2;
        const float* in[2]; u16* outp[2]; int Nd[2];
#pragma unroll
        for (int u = 0; u < 2; ++u) {
            int w = f0 + u;
            if (w < 4096) {
                int e = w >> 7, rem = w & 127, ks = rem >> 3, nt = rem & 7;
                in[u] = w1 + (size_t)e * DM * HD + (size_t)(32 * ks + q * 8) * HD + 16 * nt + m;
                Nd[u] = HD;
                outp[u] = wf1 + (size_t)w * 512 + lane * 8;
            } else {
                int wl = w - 4096, e = wl >> 7, rem = wl & 127, ks = rem >> 5, nt = rem & 31;
                in[u] = w2 + (size_t)e * HD * DM + (size_t)(32 * ks + q * 8) * DM + 16 * nt + m;
                Nd[u] = DM;
                outp[u] = wf2 + (size_t)wl * 512 + lane * 8;
            }
        }
        float v[2][8];
#pragma unroll
        for (int u = 0; u < 2; ++u)
#pragma unroll
            for (int j = 0; j < 8; ++j) v[u][j] = in[u][(size_t)j * Nd[u]];
#pragma unroll
        for (int u = 0; u < 2; ++u) {
            u16x8 h;
#pragma unroll
            for (int j = 0; j < 8; ++j) h[j] = f2bf(v[u][j]);
            *(u16x8*)outp[u] = h;
        }
        return;
    }

    // ---- router: 16 tokens/block, blocks [0,256) cover all 4096 tokens ----
    int tb = blockIdx.x * 16;
#pragma unroll
    for (int rep = 0; rep < 8; ++rep) {
        int idx = (rep * 256 + tid) * 4;            // element in 16x512 tile
        int row = idx >> 9, col = idx & 511;
        f32x4 v = *(const f32x4*)(x + (size_t)(tb + row) * DM + col);
        *(f32x4*)&xs[row][col] = v;
        u16x4 h;
#pragma unroll
        for (int j = 0; j < 4; ++j) h[j] = f2bf(v[j]);
        *(u16x4*)(xbf + (size_t)(tb + row) * DM + col) = h;
    }
    __syncthreads();

    // thread: tokens {tid&7, (tid&7)+8}, expert tid>>3; one sel stream feeds both.
    // Per-token summation order identical to the verified fp64 router:
    // 4 chains of 128 deps, combined (a0+a1)+(a2+a3).
    {
        int tok0 = tid & 7, e = tid >> 3;
        const float* sp  = sel + (size_t)e * DM;
        const float* xpA = xs[tok0];
        const float* xpB = xs[tok0 + 8];
        double a0 = 0.0, a1 = 0.0, a2 = 0.0, a3 = 0.0;
        double b0 = 0.0, b1 = 0.0, b2 = 0.0, b3 = 0.0;
#pragma unroll 4
        for (int j = 0; j < 512; j += 16) {
            f32x4 s0 = *(const f32x4*)(sp + j);
            f32x4 s1 = *(const f32x4*)(sp + j + 4);
            f32x4 s2 = *(const f32x4*)(sp + j + 8);
            f32x4 s3 = *(const f32x4*)(sp + j + 12);
            f32x4 xA0 = *(const f32x4*)(xpA + j);
            f32x4 xA1 = *(const f32x4*)(xpA + j + 4);
            f32x4 xA2 = *(const f32x4*)(xpA + j + 8);
            f32x4 xA3 = *(const f32x4*)(xpA + j + 12);
            f32x4 xB0 = *(const f32x4*)(xpB + j);
            f32x4 xB1 = *(const f32x4*)(xpB + j + 4);
            f32x4 xB2 = *(const f32x4*)(xpB + j + 8);
            f32x4 xB3 = *(const f32x4*)(xpB + j + 12);
#pragma unroll
            for (int k = 0; k < 4; ++k) {
                a0 = fma((double)xA0[k], (double)s0[k], a0);
                a1 = fma((double)xA1[k], (double)s1[k], a1);
                a2 = fma((double)xA2[k], (double)s2[k], a2);
                a3 = fma((double)xA3[k], (double)s3[k], a3);
                b0 = fma((double)xB0[k], (double)s0[k], b0);
                b1 = fma((double)xB1[k], (double)s1[k], b1);
                b2 = fma((double)xB2[k], (double)s2[k], b2);
                b3 = fma((double)xB3[k], (double)s3[k], b3);
            }
        }
        sc[tok0][e]     = (a0 + a1) + (a2 + a3);
        sc[tok0 + 8][e] = (b0 + b1) + (b2 + b3);
    }
    __syncthreads();

    // top-k per token -> LDS pick lists
    if (tid < 16) {
        unsigned mask = 0;
        for (int k = 0; k < TK; ++k) {
            double best = -1e300; int be = 0;
            for (int ee = 0; ee < NE; ++ee) {
                double v = sc[tid][ee];
                if (!((mask >> ee) & 1u) && v > best) { best = v; be = ee; }
            }
            mask |= 1u << be;
            pk_e[tid * 4 + k] = be;
            pk_g[tid * 4 + k] = 1.0f / (1.0f + __expf(-(float)best));
        }
    }
    __syncthreads();

    // per-expert aggregation: ONE atomicAdd per (block, expert), issued by 32
    // independent lanes (no dependent atomic chains, 3.5x fewer line-RMWs)
    if (tid < NE) {
        int e2 = tid, cnt = 0;
#pragma unroll
        for (int i = 0; i < 64; ++i) cnt += (pk_e[i] == e2) ? 1 : 0;
        if (cnt) {
            int base = atomicAdd(&counts_pad[32 * e2], cnt);   // own 128-B line
            int o = 0;
            for (int i = 0; i < 64; ++i) {
                if (pk_e[i] == e2) {
                    tok_list[e2 * NTOK + base + o]  = ((i & 3) << 16) | (tb + (i >> 2));
                    gate_list[e2 * NTOK + base + o] = pk_g[i];
                    ++o;
                }
            }
        }
    }
}

// ---------------- fused expert MLP (verbatim round-1: 32-row tiles) ----------------
__global__ __launch_bounds__(256, 2) void moe_mlp_kernel(const u16* __restrict__ xbf,
                                                         const u16* __restrict__ wf1,
                                                         const u16* __restrict__ wf2,
                                                         const int* __restrict__ counts_pad,
                                                         const int* __restrict__ tok_list,
                                                         const float* __restrict__ gate_list,
                                                         u16* __restrict__ part,
                                                         float* __restrict__ out,
                                                         int use_part) {
    __shared__ int   s_cnt[NE];
    __shared__ int   s_ent[32];
    __shared__ float s_gate[32];
    __shared__ __align__(16) u16 Hm[32][136];       // 272B stride
    __shared__ __align__(16) u16 Ct[32][520];       // 1040B stride

    int tid = threadIdx.x;
    if (tid < NE) s_cnt[tid] = counts_pad[32 * tid];
    __syncthreads();

    int b = blockIdx.x;
    int xcd = b & 7, idx = b >> 3;
    int e = -1, t = 0, rows = 0, pre = 0;
#pragma unroll
    for (int j = 0; j < 4; ++j) {                   // experts xcd, xcd+8, xcd+16, xcd+24
        int ee = xcd + 8 * j;
        int cc = s_cnt[ee];
        int nt = (cc + 31) >> 5;
        if (e < 0 && idx < pre + nt) { e = ee; t = idx - pre; rows = cc - t * 32; if (rows > 32) rows = 32; }
        pre += nt;
    }
    if (e < 0) return;

    if (tid < 32) {
        int base = e * NTOK + t * 32;
        bool val = tid < rows;
        s_ent[tid]  = tok_list[base + (val ? tid : 0)];
        s_gate[tid] = val ? gate_list[base + tid] : 0.0f;
    }
    __syncthreads();

    int wv = tid >> 6, lane = tid & 63, m = lane & 15, q = lane >> 4;
    int r = wv >> 1, c = wv & 1;                    // GEMM1: rows 16r..+16, cols 64c..+64
    const u16* w1f = wf1 + (size_t)e * (128 * 512);
    const u16* w2f = wf2 + (size_t)e * (128 * 512);

    const u16* a0 = xbf + (size_t)(s_ent[16 * r + m] & 0xFFFF) * DM + q * 8;

    // GEMM1: k-steps in pairs, double-buffered
    short8 ab[2][2];
    short8 bb[2][2][4];
#pragma unroll
    for (int kk = 0; kk < 2; ++kk) {
        ab[0][kk] = *(const short8*)(a0 + 32 * kk);
        const u16* bp = w1f + (size_t)kk * 4096 + (size_t)(4 * c) * 512 + lane * 8;
#pragma unroll
        for (int n = 0; n < 4; ++n) bb[0][kk][n] = *(const short8*)(bp + n * 512);
    }
    f32x4 acc[4];
#pragma unroll
    for (int n = 0; n < 4; ++n) acc[n] = (f32x4){0.f, 0.f, 0.f, 0.f};

#pragma unroll
    for (int kp = 0; kp < 8; ++kp) {
        int cur = kp & 1, nxt = cur ^ 1;
        if (kp < 7) {
            int ks0 = 2 * (kp + 1);
#pragma unroll
            for (int kk = 0; kk < 2; ++kk) {
                ab[nxt][kk] = *(const short8*)(a0 + 32 * (ks0 + kk));
                const u16* bp = w1f + (size_t)(ks0 + kk) * 4096 + (size_t)(4 * c) * 512 + lane * 8;
#pragma unroll
                for (int n = 0; n < 4; ++n) bb[nxt][kk][n] = *(const short8*)(bp + n * 512);
            }
        }
#pragma unroll
        for (int kk = 0; kk < 2; ++kk)
#pragma unroll
            for (int n = 0; n < 4; ++n)
                acc[n] = __builtin_amdgcn_mfma_f32_16x16x32_bf16(ab[cur][kk],
                                                                 bb[cur][kk][n],
                                                                 acc[n], 0, 0, 0);
    }

    // relu * gate -> Hm
    {
        int rb = 16 * r + q * 4;
#pragma unroll
        for (int n = 0; n < 4; ++n)
#pragma unroll
            for (int rr = 0; rr < 4; ++rr)
                Hm[rb + rr][64 * c + 16 * n + m] =
                    f2bf(fmaxf(acc[n][rr], 0.f) * s_gate[rb + rr]);
    }

    // GEMM2: wave owns cols [128*wv, +128); w2 frags double-buffered per k-slice.
    short8 cb[2][8];
    {
        const u16* bp = w2f + (size_t)(wv * 8) * 512 + lane * 8;
#pragma unroll
        for (int n = 0; n < 8; ++n) cb[0][n] = *(const short8*)(bp + n * 512);
    }
    __syncthreads();                                // Hm ready

    f32x4 acc2[2][8];
#pragma unroll
    for (int i = 0; i < 2; ++i)
#pragma unroll
        for (int n = 0; n < 8; ++n) acc2[i][n] = (f32x4){0.f, 0.f, 0.f, 0.f};
#pragma unroll
    for (int ks = 0; ks < 4; ++ks) {
        int cur = ks & 1, nxt = cur ^ 1;
        if (ks < 3) {
            const u16* bp = w2f + (size_t)((ks + 1) * 32 + wv * 8) * 512 + lane * 8;
#pragma unroll
            for (int n = 0; n < 8; ++n) cb[nxt][n] = *(const short8*)(bp + n * 512);
        }
        short8 h0 = *(const short8*)&Hm[m][32 * ks + q * 8];
        short8 h1 = *(const short8*)&Hm[16 + m][32 * ks + q * 8];
#pragma unroll
        for (int n = 0; n < 8; ++n) {
            acc2[0][n] = __builtin_amdgcn_mfma_f32_16x16x32_bf16(h0, cb[cur][n], acc2[0][n], 0, 0, 0);
            acc2[1][n] = __builtin_amdgcn_mfma_f32_16x16x32_bf16(h1, cb[cur][n], acc2[1][n], 0, 0, 0);
        }
    }

    // C-layout -> LDS transpose (each wave writes its 128-col stripe)
#pragma unroll
    for (int i = 0; i < 2; ++i) {
        int rb = 16 * i + q * 4;
#pragma unroll
        for (int n = 0; n < 8; ++n)
#pragma unroll
            for (int rr = 0; rr < 4; ++rr)
                Ct[rb + rr][128 * wv + 16 * n + m] = f2bf(acc2[i][n][rr]);
    }
    __syncthreads();                                // Ct complete
    // contiguous row stores: wave handles full 512-col rows
#pragma unroll
    for (int rep = 0; rep < 8; ++rep) {
        int rl = rep * 4 + wv;                      // 0..31
        u16x8 v = *(const u16x8*)&Ct[rl][lane * 8];
        if (rl < rows) {
            int en = s_ent[rl];
            int tk = en & 0xFFFF, sl2 = en >> 16;
            if (use_part) {
                *(u16x8*)(part + ((size_t)sl2 * NTOK + tk) * DM + lane * 8) = v;
            } else {
                float* op = out + (size_t)tk * DM + lane * 8;
#pragma unroll
                for (int j = 0; j < 8; ++j) atomicAdd(&op[j], bf2f(v[j]));
            }
        }
    }
}

// ---------------- combine: out[t][c] = sum_k part[k][t][c] ----------------
__global__ __launch_bounds__(256) void combine_kernel(const u16* __restrict__ part,
                                                      float* __restrict__ out) {
    size_t off = ((size_t)blockIdx.x * 256 + threadIdx.x) * 8;
    float s[8] = {0, 0, 0, 0, 0, 0, 0, 0};
#pragma unroll
    for (int k = 0; k < TK; ++k) {
        u16x8 p = *(const u16x8*)(part + (size_t)k * NTOK * DM + off);
#pragma unroll
        for (int j = 0; j < 8; ++j) s[j] += bf2f(p[j]);
    }
    *(f32x4*)(out + off)     = (f32x4){s[0], s[1], s[2], s[3]};
    *(f32x4*)(out + off + 4) = (f32x4){s[4], s[5], s[6], s[7]};
}

extern "C" void kernel_launch(void* const* d_in, const int* in_sizes, int n_in,
                              void* d_out, int out_size, void* d_ws, size_t ws_size,
                              hipStream_t stream) {
    (void)in_sizes; (void)n_in; (void)out_size;
    const float* x   = (const float*)d_in[0];   // [N, D]
    const float* sel = (const float*)d_in[1];   // [E, D]
    const float* w1  = (const float*)d_in[2];   // [E, D, H]
    const float* w2  = (const float*)d_in[3];   // [E, H, D]
    float* out = (float*)d_out;                 // [N, D]

    char* ws = (char*)d_ws;
    int*   counts_pad = (int*)(ws);                                  // 4 KB (32 lines)
    int*   tok_list   = (int*)(ws + 4096);                           // 512 KB
    float* gate_list  = (float*)(ws + 4096 + (size_t)NE * NTOK * 4); // 512 KB
    u16*   xbf  = (u16*)(ws + 4096 + (size_t)NE * NTOK * 8);         // 4 MB
    u16*   wf1  = xbf + (size_t)NTOK * DM;                           // 4 MB
    u16*   wf2  = wf1 + (size_t)NE * HD * DM;                        // 4 MB
    u16*   part = wf2 + (size_t)NE * HD * DM;                        // 16.8 MB (optional)

    size_t need = 4096 + (size_t)NE * NTOK * 8 + (size_t)NTOK * DM * 2
                + 2 * (size_t)NE * HD * DM * 2 + (size_t)TK * NTOK * DM * 2;
    int use_part = (ws_size >= need) ? 1 : 0;

    hipMemsetAsync(counts_pad, 0, 4096, stream);
    if (!use_part)
        hipMemsetAsync(d_out, 0, (size_t)NTOK * DM * sizeof(float), stream);

    // blocks [0,256) router (16 tok/block -> all 4096 tokens); [256,1280) swizzle
    prep_kernel<<<1280, 256, 0, stream>>>(x, sel, w1, w2, counts_pad, tok_list,
                                          gate_list, xbf, wf1, wf2);
    // XCD-aware grid: 8 groups x 512 worst-case 32-row tiles; empty blocks exit cheaply
    moe_mlp_kernel<<<4096, 256, 0, stream>>>(xbf, wf1, wf2, counts_pad, tok_list,
                                             gate_list, part, out, use_part);
    if (use_part)
        combine_kernel<<<NTOK * DM / 8 / 256, 256, 0, stream>>>(part, out);
}

// Round 4
// 114.197 us; speedup vs baseline: 2.1613x; 1.0790x over previous
//
#include <hip/hip_runtime.h>
#include <hip/hip_bf16.h>

// Problem constants: N tokens, D d_model, E experts, H hidden, K top-k
#define NTOK 4096
#define DM   512
#define NE   32
#define HD   128
#define TK   4
#define NRB  1024   // router blocks (4 tokens each)

typedef unsigned short u16;
typedef unsigned int   u32;
typedef u16   u16x4 __attribute__((ext_vector_type(4)));
typedef u16   u16x8 __attribute__((ext_vector_type(8)));
typedef short short8 __attribute__((ext_vector_type(8)));
typedef float f32x4 __attribute__((ext_vector_type(4)));
typedef int   int4v __attribute__((ext_vector_type(4)));

__device__ __forceinline__ u16 f2bf(float f) {
    union { float f; u32 u; } v; v.f = f;
    return (u16)((v.u + 0x7FFFu + ((v.u >> 16) & 1u)) >> 16);   // RNE
}
__device__ __forceinline__ float bf2f(u16 h) {
    union { u32 u; float f; } v; v.u = ((u32)h) << 16; return v.f;
}

// ---------------- fused prep (round-1 structure; atomic-free appends) ----------------
// blocks [0,1024):     router, 4 tokens/block; deterministic per-(block,expert) slots:
//                      tok_list[e][bl][0..3], blk_cnt[e][bl] written UNCONDITIONALLY
//                      (no zero-init needed -> no memset node, no atomics).
// blocks [1024,2048):  weight swizzle fp32 -> bf16 fragment-major (verbatim round-1)
__global__ __launch_bounds__(256) void prep_kernel(const float* __restrict__ x,
                                                   const float* __restrict__ sel,
                                                   const float* __restrict__ w1,
                                                   const float* __restrict__ w2,
                                                   int* __restrict__ blk_cnt,
                                                   int* __restrict__ tok_list,
                                                   float* __restrict__ gate_list,
                                                   u16* __restrict__ xbf,
                                                   u16* __restrict__ wf1,
                                                   u16* __restrict__ wf2) {
    __shared__ float  xs[4][520];
    __shared__ double sc[4][33];
    __shared__ int    pk_e[16];
    __shared__ float  pk_g[16];
    int tid = threadIdx.x;
    int wv = tid >> 6, lane = tid & 63;

    if (blockIdx.x >= NRB) {
        // ---- weight swizzle: 2 fragments per wave ----
        int m = lane & 15, q = lane >> 4;
        int f0 = ((blockIdx.x - NRB) * 4 + wv) * 2;
        const float* in[2]; u16* outp[2]; int Nd[2];
#pragma unroll
        for (int u = 0; u < 2; ++u) {
            int w = f0 + u;
            if (w < 4096) {
                int e = w >> 7, rem = w & 127, ks = rem >> 3, nt = rem & 7;
                in[u] = w1 + (size_t)e * DM * HD + (size_t)(32 * ks + q * 8) * HD + 16 * nt + m;
                Nd[u] = HD;
                outp[u] = wf1 + (size_t)w * 512 + lane * 8;
            } else {
                int wl = w - 4096, e = wl >> 7, rem = wl & 127, ks = rem >> 5, nt = rem & 31;
                in[u] = w2 + (size_t)e * HD * DM + (size_t)(32 * ks + q * 8) * DM + 16 * nt + m;
                Nd[u] = DM;
                outp[u] = wf2 + (size_t)wl * 512 + lane * 8;
            }
        }
        float v[2][8];
#pragma unroll
        for (int u = 0; u < 2; ++u)
#pragma unroll
            for (int j = 0; j < 8; ++j) v[u][j] = in[u][(size_t)j * Nd[u]];
#pragma unroll
        for (int u = 0; u < 2; ++u) {
            u16x8 h;
#pragma unroll
            for (int j = 0; j < 8; ++j) h[j] = f2bf(v[u][j]);
            *(u16x8*)outp[u] = h;
        }
        return;
    }

    // ---- router: 4 tokens/block (verbatim round-1 math) ----
    int bl = blockIdx.x;
    int tb = bl * 4;
#pragma unroll
    for (int rep = 0; rep < 2; ++rep) {
        int idx = (rep * 256 + tid) * 4;            // element in 4x512 tile
        int row = idx >> 9, col = idx & 511;
        f32x4 v = *(const f32x4*)(x + (size_t)(tb + row) * DM + col);
        *(f32x4*)&xs[row][col] = v;
        u16x4 h;
#pragma unroll
        for (int j = 0; j < 4; ++j) h[j] = f2bf(v[j]);
        *(u16x4*)(xbf + (size_t)(tb + row) * DM + col) = h;
    }
    __syncthreads();

    // thread: tok = tid&3, seg = (tid>>2)&1, e = tid>>3 ; 256-long fp64 dot, 4 chains
    int tok = tid & 3, seg = (tid >> 2) & 1, e = tid >> 3;
    const float* sp = sel + (size_t)e * DM + seg * 256;
    const float* xp = &xs[tok][seg * 256];
    double pa = 0.0, pb = 0.0, pc = 0.0, pd = 0.0;
#pragma unroll 4
    for (int j = 0; j < 256; j += 16) {
        f32x4 x0 = *(const f32x4*)(xp + j);
        f32x4 x1 = *(const f32x4*)(xp + j + 4);
        f32x4 x2 = *(const f32x4*)(xp + j + 8);
        f32x4 x3 = *(const f32x4*)(xp + j + 12);
        f32x4 s0 = *(const f32x4*)(sp + j);
        f32x4 s1 = *(const f32x4*)(sp + j + 4);
        f32x4 s2 = *(const f32x4*)(sp + j + 8);
        f32x4 s3 = *(const f32x4*)(sp + j + 12);
#pragma unroll
        for (int k = 0; k < 4; ++k) {
            pa = fma((double)x0[k], (double)s0[k], pa);
            pb = fma((double)x1[k], (double)s1[k], pb);
            pc = fma((double)x2[k], (double)s2[k], pc);
            pd = fma((double)x3[k], (double)s3[k], pd);
        }
    }
    double p = (pa + pb) + (pc + pd);
    p += __shfl_xor(p, 4);                          // combine the two K-halves
    if (seg == 0) sc[tok][e] = p;
    __syncthreads();

    // top-k per token -> LDS pick lists (math identical to round-1)
    if (tid < 4) {
        unsigned mask = 0;
        for (int k = 0; k < TK; ++k) {
            double best = -1e300; int be = 0;
            for (int ee = 0; ee < NE; ++ee) {
                double v = sc[tid][ee];
                if (!((mask >> ee) & 1u) && v > best) { best = v; be = ee; }
            }
            mask |= 1u << be;
            pk_e[tid * 4 + k] = be;
            pk_g[tid * 4 + k] = 1.0f / (1.0f + __expf(-(float)best));
        }
    }
    __syncthreads();

    // deterministic append: expert tid owns region tok_list[(tid*NRB+bl)*4 ..]
    if (tid < NE) {
        int e2 = tid, cnt = 0;
        int base = (e2 * NRB + bl) * 4;
#pragma unroll
        for (int i = 0; i < 16; ++i) {
            if (pk_e[i] == e2) {
                tok_list[base + cnt]  = ((i & 3) << 16) | (tb + (i >> 2));
                gate_list[base + cnt] = pk_g[i];
                ++cnt;
            }
        }
        blk_cnt[e2 * NRB + bl] = cnt;               // written for EVERY (e,bl)
    }
}

// ---------------- fused expert MLP ----------------
// Grid 1024 (8 XCD groups x 128), internal tile loop. Per-expert totals and token
// positions reconstructed from blk_cnt via shfl-reduce + exclusive prefix scan +
// binary-search gather (all L2-hot; replaces global counts/atomics).
__global__ __launch_bounds__(256, 2) void moe_mlp_kernel(const u16* __restrict__ xbf,
                                                         const u16* __restrict__ wf1,
                                                         const u16* __restrict__ wf2,
                                                         const int* __restrict__ blk_cnt,
                                                         const int* __restrict__ tok_list,
                                                         const float* __restrict__ gate_list,
                                                         u16* __restrict__ part,
                                                         float* __restrict__ out,
                                                         int use_part) {
    __shared__ int   s_tot[4];
    __shared__ int   s_red[4][4];                   // [wave][expert-slot]
    __shared__ int   s_pref[NRB + 1];               // 4.1 KB
    __shared__ int   s_ent[32];
    __shared__ float s_gate[32];
    __shared__ __align__(16) u16 Hm[32][136];       // 272B stride
    __shared__ __align__(16) u16 Ct[32][520];       // 1040B stride

    int tid = threadIdx.x;
    int wv = tid >> 6, lane = tid & 63;
    int xcd = blockIdx.x & 7, idx0 = blockIdx.x >> 3;   // 128 blocks per group

    // ---- per-expert totals for this group's 4 experts ----
    int lsums[4];
#pragma unroll
    for (int j = 0; j < 4; ++j) {
        int4v v = *(const int4v*)&blk_cnt[(size_t)(xcd + 8 * j) * NRB + tid * 4];
        lsums[j] = v[0] + v[1] + v[2] + v[3];
    }
#pragma unroll
    for (int j = 0; j < 4; ++j) {
        int s = lsums[j];
#pragma unroll
        for (int off = 32; off >= 1; off >>= 1) s += __shfl_down(s, off);
        if (lane == 0) s_red[wv][j] = s;
    }
    __syncthreads();
    if (tid < 4) s_tot[tid] = s_red[0][tid] + s_red[1][tid] + s_red[2][tid] + s_red[3][tid];
    __syncthreads();

    int c0 = s_tot[0], c1 = s_tot[1], c2 = s_tot[2], c3 = s_tot[3];
    int n0 = (c0 + 31) >> 5, n1 = (c1 + 31) >> 5, n2 = (c2 + 31) >> 5, n3 = (c3 + 31) >> 5;
    int tot = n0 + n1 + n2 + n3;

    int m = lane & 15, q = lane >> 4;
    int r = wv >> 1, c = wv & 1;                    // GEMM1: rows 16r..+16, cols 64c..+64
    int e_last = -1;

    for (int idx = idx0; idx < tot; idx += 128) {
        int e2, t2, cc;
        if (idx < n0)                { e2 = xcd;      t2 = idx;                cc = c0; }
        else if (idx < n0 + n1)      { e2 = xcd + 8;  t2 = idx - n0;           cc = c1; }
        else if (idx < n0 + n1 + n2) { e2 = xcd + 16; t2 = idx - n0 - n1;      cc = c2; }
        else                         { e2 = xcd + 24; t2 = idx - n0 - n1 - n2; cc = c3; }
        int rows = cc - t2 * 32; if (rows > 32) rows = 32;

        __syncthreads();                            // prev iter's Ct/s_ent readers done

        if (e2 != e_last) {
            // exclusive prefix scan of blk_cnt[e2][0..NRB) into s_pref
            int4v v = *(const int4v*)&blk_cnt[(size_t)e2 * NRB + tid * 4];
            int lsum = v[0] + v[1] + v[2] + v[3];
            int incl = lsum;
#pragma unroll
            for (int off = 1; off < 64; off <<= 1) {
                int t3 = __shfl_up(incl, off);
                if (lane >= off) incl += t3;
            }
            if (lane == 63) s_red[0][wv] = incl;
            __syncthreads();
            int woff = 0;
#pragma unroll
            for (int w2 = 0; w2 < 4; ++w2) if (w2 < wv) woff += s_red[0][w2];
            int excl = woff + incl - lsum;
            s_pref[tid * 4 + 0] = excl;
            s_pref[tid * 4 + 1] = excl + v[0];
            s_pref[tid * 4 + 2] = excl + v[0] + v[1];
            s_pref[tid * 4 + 3] = excl + v[0] + v[1] + v[2];
            if (tid == 255) s_pref[NRB] = excl + lsum;
            e_last = e2;
            __syncthreads();
        }

        // gather this tile's 32 entries via binary search on s_pref
        if (tid < 32) {
            int row = t2 * 32 + tid;
            bool val = tid < rows;
            int rr = val ? row : 0;
            int lo = 0, hi = NRB;
            while (hi - lo > 1) { int mid = (lo + hi) >> 1; if (s_pref[mid] <= rr) lo = mid; else hi = mid; }
            int sub = rr - s_pref[lo];
            s_ent[tid]  = tok_list[((size_t)e2 * NRB + lo) * 4 + sub];
            s_gate[tid] = val ? gate_list[((size_t)e2 * NRB + lo) * 4 + sub] : 0.0f;
        }
        __syncthreads();

        const u16* w1f = wf1 + (size_t)e2 * (128 * 512);
        const u16* w2f = wf2 + (size_t)e2 * (128 * 512);
        const u16* a0 = xbf + (size_t)(s_ent[16 * r + m] & 0xFFFF) * DM + q * 8;

        // GEMM1: k-steps in pairs, double-buffered
        short8 ab[2][2];
        short8 bb[2][2][4];
#pragma unroll
        for (int kk = 0; kk < 2; ++kk) {
            ab[0][kk] = *(const short8*)(a0 + 32 * kk);
            const u16* bp = w1f + (size_t)kk * 4096 + (size_t)(4 * c) * 512 + lane * 8;
#pragma unroll
            for (int n = 0; n < 4; ++n) bb[0][kk][n] = *(const short8*)(bp + n * 512);
        }
        f32x4 acc[4];
#pragma unroll
        for (int n = 0; n < 4; ++n) acc[n] = (f32x4){0.f, 0.f, 0.f, 0.f};

#pragma unroll
        for (int kp = 0; kp < 8; ++kp) {
            int cur = kp & 1, nxt = cur ^ 1;
            if (kp < 7) {
                int ks0 = 2 * (kp + 1);
#pragma unroll
                for (int kk = 0; kk < 2; ++kk) {
                    ab[nxt][kk] = *(const short8*)(a0 + 32 * (ks0 + kk));
                    const u16* bp = w1f + (size_t)(ks0 + kk) * 4096 + (size_t)(4 * c) * 512 + lane * 8;
#pragma unroll
                    for (int n = 0; n < 4; ++n) bb[nxt][kk][n] = *(const short8*)(bp + n * 512);
                }
            }
#pragma unroll
            for (int kk = 0; kk < 2; ++kk)
#pragma unroll
                for (int n = 0; n < 4; ++n)
                    acc[n] = __builtin_amdgcn_mfma_f32_16x16x32_bf16(ab[cur][kk],
                                                                     bb[cur][kk][n],
                                                                     acc[n], 0, 0, 0);
        }

        // relu * gate -> Hm
        {
            int rb = 16 * r + q * 4;
#pragma unroll
            for (int n = 0; n < 4; ++n)
#pragma unroll
                for (int rr2 = 0; rr2 < 4; ++rr2)
                    Hm[rb + rr2][64 * c + 16 * n + m] =
                        f2bf(fmaxf(acc[n][rr2], 0.f) * s_gate[rb + rr2]);
        }

        // GEMM2: wave owns cols [128*wv, +128); w2 frags double-buffered per k-slice
        short8 cb[2][8];
        {
            const u16* bp = w2f + (size_t)(wv * 8) * 512 + lane * 8;
#pragma unroll
            for (int n = 0; n < 8; ++n) cb[0][n] = *(const short8*)(bp + n * 512);
        }
        __syncthreads();                            // Hm ready

        f32x4 acc2[2][8];
#pragma unroll
        for (int i = 0; i < 2; ++i)
#pragma unroll
            for (int n = 0; n < 8; ++n) acc2[i][n] = (f32x4){0.f, 0.f, 0.f, 0.f};
#pragma unroll
        for (int ks = 0; ks < 4; ++ks) {
            int cur = ks & 1, nxt = cur ^ 1;
            if (ks < 3) {
                const u16* bp = w2f + (size_t)((ks + 1) * 32 + wv * 8) * 512 + lane * 8;
#pragma unroll
                for (int n = 0; n < 8; ++n) cb[nxt][n] = *(const short8*)(bp + n * 512);
            }
            short8 h0 = *(const short8*)&Hm[m][32 * ks + q * 8];
            short8 h1 = *(const short8*)&Hm[16 + m][32 * ks + q * 8];
#pragma unroll
            for (int n = 0; n < 8; ++n) {
                acc2[0][n] = __builtin_amdgcn_mfma_f32_16x16x32_bf16(h0, cb[cur][n], acc2[0][n], 0, 0, 0);
                acc2[1][n] = __builtin_amdgcn_mfma_f32_16x16x32_bf16(h1, cb[cur][n], acc2[1][n], 0, 0, 0);
            }
        }

        // C-layout -> LDS transpose (each wave writes its 128-col stripe)
#pragma unroll
        for (int i = 0; i < 2; ++i) {
            int rb = 16 * i + q * 4;
#pragma unroll
            for (int n = 0; n < 8; ++n)
#pragma unroll
                for (int rr2 = 0; rr2 < 4; ++rr2)
                    Ct[rb + rr2][128 * wv + 16 * n + m] = f2bf(acc2[i][n][rr2]);
        }
        __syncthreads();                            // Ct complete
        // contiguous row stores
#pragma unroll
        for (int rep = 0; rep < 8; ++rep) {
            int rl = rep * 4 + wv;                  // 0..31
            u16x8 v = *(const u16x8*)&Ct[rl][lane * 8];
            if (rl < rows) {
                int en = s_ent[rl];
                int tk = en & 0xFFFF, sl2 = en >> 16;
                if (use_part) {
                    *(u16x8*)(part + ((size_t)sl2 * NTOK + tk) * DM + lane * 8) = v;
                } else {
                    float* op = out + (size_t)tk * DM + lane * 8;
#pragma unroll
                    for (int j = 0; j < 8; ++j) atomicAdd(&op[j], bf2f(v[j]));
                }
            }
        }
    }
}

// ---------------- combine: out[t][c] = sum_k part[k][t][c] ----------------
__global__ __launch_bounds__(256) void combine_kernel(const u16* __restrict__ part,
                                                      float* __restrict__ out) {
    size_t off = ((size_t)blockIdx.x * 256 + threadIdx.x) * 8;
    float s[8] = {0, 0, 0, 0, 0, 0, 0, 0};
#pragma unroll
    for (int k = 0; k < TK; ++k) {
        u16x8 p = *(const u16x8*)(part + (size_t)k * NTOK * DM + off);
#pragma unroll
        for (int j = 0; j < 8; ++j) s[j] += bf2f(p[j]);
    }
    *(f32x4*)(out + off)     = (f32x4){s[0], s[1], s[2], s[3]};
    *(f32x4*)(out + off + 4) = (f32x4){s[4], s[5], s[6], s[7]};
}

extern "C" void kernel_launch(void* const* d_in, const int* in_sizes, int n_in,
                              void* d_out, int out_size, void* d_ws, size_t ws_size,
                              hipStream_t stream) {
    (void)in_sizes; (void)n_in; (void)out_size;
    const float* x   = (const float*)d_in[0];   // [N, D]
    const float* sel = (const float*)d_in[1];   // [E, D]
    const float* w1  = (const float*)d_in[2];   // [E, D, H]
    const float* w2  = (const float*)d_in[3];   // [E, H, D]
    float* out = (float*)d_out;                 // [N, D]

    char* ws = (char*)d_ws;
    int*   blk_cnt   = (int*)(ws);                                   // 128 KB
    int*   tok_list  = (int*)(ws + (size_t)NE * NRB * 4);            // 512 KB
    float* gate_list = (float*)(ws + (size_t)NE * NRB * 4 * 5);      // 512 KB
    u16*   xbf  = (u16*)(ws + (size_t)NE * NRB * 4 * 9);             // 4 MB
    u16*   wf1  = xbf + (size_t)NTOK * DM;                           // 4 MB
    u16*   wf2  = wf1 + (size_t)NE * HD * DM;                        // 4 MB
    u16*   part = wf2 + (size_t)NE * HD * DM;                        // 16.8 MB

    size_t need = (size_t)NE * NRB * 4 * 9 + (size_t)NTOK * DM * 2
                + 2 * (size_t)NE * HD * DM * 2 + (size_t)TK * NTOK * DM * 2;
    int use_part = (ws_size >= need) ? 1 : 0;

    if (!use_part)
        hipMemsetAsync(d_out, 0, (size_t)NTOK * DM * sizeof(float), stream);

    // blocks [0,1024) router; [1024,2048) swizzle. No memset node (no atomics,
    // blk_cnt written unconditionally for every (expert, block)).
    prep_kernel<<<2048, 256, 0, stream>>>(x, sel, w1, w2, blk_cnt, tok_list,
                                          gate_list, xbf, wf1, wf2);
    // 8 XCD groups x 128 blocks, internal tile loop covers any count skew
    moe_mlp_kernel<<<1024, 256, 0, stream>>>(xbf, wf1, wf2, blk_cnt, tok_list,
                                             gate_list, part, out, use_part);
    if (use_part)
        combine_kernel<<<NTOK * DM / 8 / 256, 256, 0, stream>>>(part, out);
}